// Round 6
// baseline (137.587 us; speedup 1.0000x reference)
//
#include <hip/hip_runtime.h>
#include <hip/hip_bf16.h>

typedef float f32x4 __attribute__((ext_vector_type(4)));
typedef short s16x8 __attribute__((ext_vector_type(8)));

#define SIGC 2379
#define KPAD 2432
#define NKT  76          // KPAD/32 k-tiles
#define NKT_HALF 38      // per split-K half
#define SROW 2440        // padded LDS row
#define NPATH 12800

// Tiled layout for A and W (bf16): element (row r, k) lives at
//   ((r>>4)*NKT + (k>>5))*512 + ((k>>3)&3)*128 + (r&15)*8 + (k&7)
// 1KB tiles of [ks(4)][R(16)][kw(8)] — fragment-ready for 16x16x32 MFMA,
// loadable with one lane-linear global_load_lds per tile.

__device__ inline void split2(float v, __hip_bfloat16* h, __hip_bfloat16* l) {
    __hip_bfloat16 hh = __float2bfloat16(v);
    *h = hh;
    *l = __float2bfloat16(v - __bfloat162float(hh));
}

__device__ inline void gload_lds16(const __hip_bfloat16* g, __hip_bfloat16* l) {
    __builtin_amdgcn_global_load_lds(
        (const __attribute__((address_space(1))) void*)g,
        (__attribute__((address_space(3))) void*)l,
        16, 0, 0);
}

// ---------------------------------------------------------------------------
// W convert: W[256][2379] fp32 -> tiled Wh/Wl bf16 hi+lo (pad zeroed)
// ---------------------------------------------------------------------------
__global__ __launch_bounds__(256) void wconv_kernel(const float* __restrict__ W,
                                                    __hip_bfloat16* __restrict__ Wh,
                                                    __hip_bfloat16* __restrict__ Wl)
{
    int k = blockIdx.x * 256 + threadIdx.x;
    int n = blockIdx.y;
    if (k >= KPAD) return;
    float v = (k < SIGC) ? W[(size_t)n * SIGC + k] : 0.0f;
    size_t off = ((size_t)(n >> 4) * NKT + (k >> 5)) * 512 + ((k >> 3) & 3) * 128 + (n & 15) * 8 + (k & 7);
    split2(v, &Wh[off], &Wl[off]);
}

// ---------------------------------------------------------------------------
// Signature kernel: 4 waves/block, 4 pp-phases; at phase pp wave w computes
// path row = pp*4 + w, so the 4 live rows are consecutive -> cooperative
// 64B-contiguous copy-out. Register-only Chen scan; lane owns pairs
// p in {lane, lane+64, lane+128(<169)}.
// s3[ijk] += dx[k] * (s2[ij] + 0.5*dx[j]*(s1[i] + dx[i]/3))
// ---------------------------------------------------------------------------
__global__ __launch_bounds__(256) void sig_kernel(const float* __restrict__ x,
                                                  __hip_bfloat16* __restrict__ Ah,
                                                  __hip_bfloat16* __restrict__ Al_,
                                                  int r_start)
{
    __shared__ float inc_s[4][5][16];                        // [wave][step][channel]
    __shared__ __align__(16) __hip_bfloat16 hi_s[4][SROW];   // [wave] = row 4*pp+w
    __shared__ __align__(16) __hip_bfloat16 lo_s[4][SROW];

    const int t = threadIdx.x;
    const int w = t >> 6;
    const int lane = t & 63;

    const int p0 = lane;
    const int p1 = lane + 64;
    const int p2 = lane + 128;
    const bool has2 = (p2 < 169);
    const int i0 = p0 / 13, j0 = p0 - i0 * 13;
    const int i1 = p1 / 13, j1 = p1 - i1 * 13;
    const int i2 = p2 / 13, j2 = p2 - i2 * 13;   // used under has2

    for (int pp = 0; pp < 4; ++pp) {
        const int r = r_start + blockIdx.x * 16 + pp * 4 + w;
        const int nn = r & 7;
        const int jj = (r >> 3) & 63;
        const int ii = r >> 9;

        __syncthreads();   // guard inc_s / hi_s / lo_s reuse across pp
        if (lane < 13) {
            if (lane < 12) {
                const float* px = x + ((size_t)(nn * 12 + lane) * 1600 + ii * 64 + jj) * 5;
                float prev = 0.0f;
                #pragma unroll
                for (int l = 0; l < 5; ++l) {
                    float v = px[l];
                    inc_s[w][l][lane] = v - prev;
                    prev = v;
                }
            } else {
                inc_s[w][0][12] = 0.0f;
                #pragma unroll
                for (int l = 1; l < 5; ++l) inc_s[w][l][12] = 0.25f;
            }
        }
        __syncthreads();

        float s1i0 = 0.0f, s1i1 = 0.0f, s1i2 = 0.0f;
        float s2p0 = 0.0f, s2p1 = 0.0f, s2p2 = 0.0f;
        float s1own = 0.0f;
        float s3a[13], s3b[13], s3c[13];
        #pragma unroll
        for (int k = 0; k < 13; ++k) { s3a[k] = 0.0f; s3b[k] = 0.0f; s3c[k] = 0.0f; }

        for (int l = 0; l < 5; ++l) {
            float dxl[13];
            #pragma unroll
            for (int k = 0; k < 13; ++k) dxl[k] = inc_s[w][l][k];

            {   // pair 0
                float dxi = inc_s[w][l][i0];
                float dxj = inc_s[w][l][j0];
                float C   = s2p0 + 0.5f * dxj * (s1i0 + dxi * (1.0f / 3.0f));
                #pragma unroll
                for (int k = 0; k < 13; ++k) s3a[k] += dxl[k] * C;
                s2p0 += s1i0 * dxj + 0.5f * dxi * dxj;
                s1i0 += dxi;
            }
            {   // pair 1
                float dxi = inc_s[w][l][i1];
                float dxj = inc_s[w][l][j1];
                float C   = s2p1 + 0.5f * dxj * (s1i1 + dxi * (1.0f / 3.0f));
                #pragma unroll
                for (int k = 0; k < 13; ++k) s3b[k] += dxl[k] * C;
                s2p1 += s1i1 * dxj + 0.5f * dxi * dxj;
                s1i1 += dxi;
            }
            if (has2) {   // pair 2
                float dxi = inc_s[w][l][i2];
                float dxj = inc_s[w][l][j2];
                float C   = s2p2 + 0.5f * dxj * (s1i2 + dxi * (1.0f / 3.0f));
                #pragma unroll
                for (int k = 0; k < 13; ++k) s3c[k] += dxl[k] * C;
                s2p2 += s1i2 * dxj + 0.5f * dxi * dxj;
                s1i2 += dxi;
            }
            if (lane < 13) s1own += inc_s[w][l][lane];
        }

        // ---- write sig row into this wave's LDS row (hi/lo) ----
        if (lane < 13) split2(s1own, &hi_s[w][lane], &lo_s[w][lane]);
        split2(s2p0, &hi_s[w][13 + p0], &lo_s[w][13 + p0]);
        split2(s2p1, &hi_s[w][13 + p1], &lo_s[w][13 + p1]);
        if (has2) split2(s2p2, &hi_s[w][13 + p2], &lo_s[w][13 + p2]);
        #pragma unroll
        for (int k = 0; k < 13; ++k) split2(s3a[k], &hi_s[w][182 + p0 * 13 + k], &lo_s[w][182 + p0 * 13 + k]);
        #pragma unroll
        for (int k = 0; k < 13; ++k) split2(s3b[k], &hi_s[w][182 + p1 * 13 + k], &lo_s[w][182 + p1 * 13 + k]);
        if (has2) {
            #pragma unroll
            for (int k = 0; k < 13; ++k) split2(s3c[k], &hi_s[w][182 + p2 * 13 + k], &lo_s[w][182 + p2 * 13 + k]);
        }
        if (lane < KPAD - SIGC) {   // zero pad 2379..2431
            hi_s[w][SIGC + lane] = __float2bfloat16(0.0f);
            lo_s[w][SIGC + lane] = __float2bfloat16(0.0f);
        }

        __syncthreads();   // all 4 rows complete before cooperative copy-out

        // ---- block-cooperative coalesced copy-out (64B bursts) ----
        const int rtl = blockIdx.x;
        const int rr = t & 3, ks = (t >> 2) & 3, ts = t >> 4;
        #pragma unroll
        for (int it2 = 0; it2 < 5; ++it2) {
            int kt = it2 * 16 + ts;
            if (kt < NKT) {
                size_t off = ((size_t)rtl * NKT + kt) * 512 + ks * 128 + (pp * 4 + rr) * 8;
                int lidx = kt * 32 + ks * 8;
                *reinterpret_cast<int4*>(Ah + off)  = *reinterpret_cast<const int4*>(&hi_s[rr][lidx]);
                *reinterpret_cast<int4*>(Al_ + off) = *reinterpret_cast<const int4*>(&lo_s[rr][lidx]);
            }
        }
    }
}

// ---------------------------------------------------------------------------
// Split-bf16 GEMM, split-K=2: P[ks][m][o] = sum_{k in half} AhWh+AhWl+AlWh.
// BM=64, BN=64; grid = (cnt/64) * 4n * 2k blocks (g=bid>>3, s=bid&7).
// 4 waves as 2m x 2n (each 32x32 = 2x2 frags); double-buffered LDS (32KB);
// 1KB-tile lane-linear global_load_lds staging; coalesced fp32 P stores.
// ---------------------------------------------------------------------------
__global__ __launch_bounds__(256) void gemm_kernel(const __hip_bfloat16* __restrict__ Ah,
                                                   const __hip_bfloat16* __restrict__ Al_,
                                                   const __hip_bfloat16* __restrict__ Wh,
                                                   const __hip_bfloat16* __restrict__ Wl,
                                                   float* __restrict__ P,
                                                   int chunk_alloc)
{
    __shared__ __align__(16) __hip_bfloat16 L[2][16 * 512];   // 32 KB

    const int bid = blockIdx.x;
    const int mIdx = bid >> 3;
    const int s = bid & 7;
    const int n2 = s & 3;        // n-block (64 outputs)
    const int ksp = s >> 2;      // k-split half

    const int t = threadIdx.x;
    const int lane = t & 63;
    const int w = t >> 6;
    const int wm = w >> 1, wn = w & 1;
    const int rt0 = mIdx * 4;        // 4 m-row-tiles
    const int nt0 = n2 * 4;          // 4 n-row-tiles
    const int kt0 = ksp * NKT_HALF;

    f32x4 acc[2][2] = {};

    // wave w stages tiles tt = w*4+s2: 0-3 Ah | 4-7 Al | 8-11 Wh | 12-15 Wl
    auto stage = [&](int buf, int kt) {
        #pragma unroll
        for (int s2 = 0; s2 < 4; ++s2) {
            int tt = w * 4 + s2;
            const __hip_bfloat16* g;
            if (tt < 4)       g = Ah  + ((size_t)(rt0 + tt)      * NKT + kt) * 512;
            else if (tt < 8)  g = Al_ + ((size_t)(rt0 + tt - 4)  * NKT + kt) * 512;
            else if (tt < 12) g = Wh  + ((size_t)(nt0 + tt - 8)  * NKT + kt) * 512;
            else              g = Wl  + ((size_t)(nt0 + tt - 12) * NKT + kt) * 512;
            gload_lds16(g + lane * 8, &L[buf][tt * 512]);
        }
    };

    stage(0, kt0);
    int cur = 0;
    __syncthreads();

    for (int kk = 0; kk < NKT_HALF; ++kk) {
        if (kk + 1 < NKT_HALF) stage(cur ^ 1, kt0 + kk + 1);   // issue-early prefetch

        const int fb = (lane >> 4) * 128 + (lane & 15) * 8;
        s16x8 ah[2], al4[2], bh[2], bl4[2];
        #pragma unroll
        for (int mm = 0; mm < 2; ++mm) {
            int base = (2 * wm + mm) * 512 + fb;
            ah[mm]  = *reinterpret_cast<const s16x8*>(&L[cur][base]);
            al4[mm] = *reinterpret_cast<const s16x8*>(&L[cur][2048 + base]);
        }
        #pragma unroll
        for (int nn = 0; nn < 2; ++nn) {
            int base = (8 + 2 * wn + nn) * 512 + fb;
            bh[nn]  = *reinterpret_cast<const s16x8*>(&L[cur][base]);
            bl4[nn] = *reinterpret_cast<const s16x8*>(&L[cur][2048 + base]);
        }

        #pragma unroll
        for (int mm = 0; mm < 2; ++mm)
            #pragma unroll
            for (int nn = 0; nn < 2; ++nn) {
                acc[mm][nn] = __builtin_amdgcn_mfma_f32_16x16x32_bf16(ah[mm],  bh[nn],  acc[mm][nn], 0, 0, 0);
                acc[mm][nn] = __builtin_amdgcn_mfma_f32_16x16x32_bf16(ah[mm],  bl4[nn], acc[mm][nn], 0, 0, 0);
                acc[mm][nn] = __builtin_amdgcn_mfma_f32_16x16x32_bf16(al4[mm], bh[nn],  acc[mm][nn], 0, 0, 0);
            }

        __syncthreads();
        cur ^= 1;
    }

    // ---- epilogue: coalesced fp32 partial stores ----
    // C/D layout: col=lane&15, row=(lane>>4)*4+reg
    float* Pb = P + ((size_t)ksp * chunk_alloc + mIdx * 64) * 256 + n2 * 64;
    #pragma unroll
    for (int mm = 0; mm < 2; ++mm)
        #pragma unroll
        for (int nn = 0; nn < 2; ++nn) {
            int o = wn * 32 + nn * 16 + (lane & 15);
            #pragma unroll
            for (int rr = 0; rr < 4; ++rr) {
                int p = wm * 32 + mm * 16 + (lane >> 4) * 4 + rr;
                Pb[(size_t)p * 256 + o] = acc[mm][nn][rr];
            }
        }
}

// ---------------------------------------------------------------------------
// Reduce: out = P0 + P1 + bias, scattered to out[ni][o][ii][jj].
// One block per 64-path m-block; float4 out stores; P reads are 2x512B
// segments per wave-instr (L2-hot).
// ---------------------------------------------------------------------------
__global__ __launch_bounds__(256) void reduce_kernel(const float* __restrict__ P,
                                                     const float* __restrict__ b,
                                                     float* __restrict__ out,
                                                     int chunk_alloc, int r_start)
{
    const int mb = blockIdx.x;
    const int pbase = r_start + mb * 64;
    const int ii = pbase >> 9;
    const int jj0 = (pbase >> 3) & 63;
    const int t = threadIdx.x;
    const int ol = t >> 1, hh = t & 1;

    const float* P0 = P + (size_t)mb * 64 * 256;
    const float* P1 = P0 + (size_t)chunk_alloc * 256;

    #pragma unroll
    for (int oh = 0; oh < 2; ++oh) {
        int o = oh * 128 + ol;
        float bo = b[o];
        #pragma unroll
        for (int c = 0; c < 4; ++c) {
            int ni = hh * 4 + c;
            float v[8];
            #pragma unroll
            for (int qq = 0; qq < 8; ++qq) {
                size_t idx = (size_t)(qq * 8 + ni) * 256 + o;
                v[qq] = P0[idx] + P1[idx] + bo;
            }
            float* dst = out + (size_t)(ni * 256 + o) * 1600 + ii * 64 + jj0;
            *reinterpret_cast<float4*>(dst)     = make_float4(v[0], v[1], v[2], v[3]);
            *reinterpret_cast<float4*>(dst + 4) = make_float4(v[4], v[5], v[6], v[7]);
        }
    }
}

// ---------------------------------------------------------------------------
extern "C" void kernel_launch(void* const* d_in, const int* in_sizes, int n_in,
                              void* d_out, int out_size, void* d_ws, size_t ws_size,
                              hipStream_t stream)
{
    const float* x = (const float*)d_in[0];
    const float* W = (const float*)d_in[1];
    const float* b = (const float*)d_in[2];
    float* out = (float*)d_out;

    char* ws = (char*)d_ws;
    __hip_bfloat16* Wh = (__hip_bfloat16*)ws;
    __hip_bfloat16* Wl = Wh + (size_t)16 * NKT * 512;
    size_t a_off = (((size_t)16 * NKT * 512 * 2 * 2) + 255) & ~(size_t)255;

    // per-chunk bytes: A hi/lo (KPAD*2*2) + P fp32 (2*256*4)
    size_t avail = (ws_size > a_off) ? ws_size - a_off : 0;
    long long maxp = (long long)(avail / ((size_t)KPAD * 4 + 2048));
    int chunk = (int)((maxp / 64) * 64);
    if (chunk > NPATH) chunk = NPATH;
    if (chunk < 64) chunk = 64;

    __hip_bfloat16* Ah = (__hip_bfloat16*)(ws + a_off);
    __hip_bfloat16* Al_ = Ah + (size_t)chunk * KPAD;
    float* P = (float*)(Al_ + (size_t)chunk * KPAD);

    wconv_kernel<<<dim3(10, 256), 256, 0, stream>>>(W, Wh, Wl);

    for (int r0 = 0; r0 < NPATH; r0 += chunk) {
        int cnt = NPATH - r0;
        if (cnt > chunk) cnt = chunk;
        sig_kernel<<<dim3(cnt / 16), 256, 0, stream>>>(x, Ah, Al_, r0);
        gemm_kernel<<<dim3((cnt / 64) * 8), 256, 0, stream>>>(Ah, Al_, Wh, Wl, P, chunk);
        reduce_kernel<<<dim3(cnt / 64), 256, 0, stream>>>(P, b, out, chunk, r0);
    }
}

// Round 7
// 124.756 us; speedup vs baseline: 1.1029x; 1.1029x over previous
//
#include <hip/hip_runtime.h>
#include <hip/hip_bf16.h>

typedef float f32x4 __attribute__((ext_vector_type(4)));
typedef short s16x8 __attribute__((ext_vector_type(8)));

#define SIGC 2379
#define KPAD 2432
#define NKT  76          // KPAD/32 k-tiles
#define NKT_HALF 38      // per split-K half
#define SROW 2440        // padded LDS row
#define NPATH 12800

// Tiled layout for A and W (bf16): element (row r, k) lives at
//   ((r>>4)*NKT + (k>>5))*512 + ((k>>3)&3)*128 + (r&15)*8 + (k&7)
// 1KB tiles of [ks(4)][R(16)][kw(8)] — fragment-ready for 16x16x32 MFMA,
// loadable with one lane-linear global_load_lds per tile.

__device__ inline void split2(float v, __hip_bfloat16* h, __hip_bfloat16* l) {
    __hip_bfloat16 hh = __float2bfloat16(v);
    *h = hh;
    *l = __float2bfloat16(v - __bfloat162float(hh));
}

__device__ inline void gload_lds16(const __hip_bfloat16* g, __hip_bfloat16* l) {
    __builtin_amdgcn_global_load_lds(
        (const __attribute__((address_space(1))) void*)g,
        (__attribute__((address_space(3))) void*)l,
        16, 0, 0);
}

// ---------------------------------------------------------------------------
// W convert: W[256][2379] fp32 -> tiled Wh/Wl bf16 hi+lo (pad zeroed)
// ---------------------------------------------------------------------------
__global__ __launch_bounds__(256) void wconv_kernel(const float* __restrict__ W,
                                                    __hip_bfloat16* __restrict__ Wh,
                                                    __hip_bfloat16* __restrict__ Wl)
{
    int k = blockIdx.x * 256 + threadIdx.x;
    int n = blockIdx.y;
    if (k >= KPAD) return;
    float v = (k < SIGC) ? W[(size_t)n * SIGC + k] : 0.0f;
    size_t off = ((size_t)(n >> 4) * NKT + (k >> 5)) * 512 + ((k >> 3) & 3) * 128 + (n & 15) * 8 + (k & 7);
    split2(v, &Wh[off], &Wl[off]);
}

// ---------------------------------------------------------------------------
// Signature kernel: 4 waves/block, 4 pp-phases; at phase pp wave w computes
// path row = pp*4 + w, so the 4 live rows are consecutive -> cooperative
// 64B-contiguous copy-out. Register-only Chen scan; lane owns pairs
// p in {lane, lane+64, lane+128(<169)}.
// s3[ijk] += dx[k] * (s2[ij] + 0.5*dx[j]*(s1[i] + dx[i]/3))
// ---------------------------------------------------------------------------
__global__ __launch_bounds__(256) void sig_kernel(const float* __restrict__ x,
                                                  __hip_bfloat16* __restrict__ Ah,
                                                  __hip_bfloat16* __restrict__ Al_,
                                                  int r_start)
{
    __shared__ float inc_s[4][5][16];                        // [wave][step][channel]
    __shared__ __align__(16) __hip_bfloat16 hi_s[4][SROW];   // [wave] = row 4*pp+w
    __shared__ __align__(16) __hip_bfloat16 lo_s[4][SROW];

    const int t = threadIdx.x;
    const int w = t >> 6;
    const int lane = t & 63;

    const int p0 = lane;
    const int p1 = lane + 64;
    const int p2 = lane + 128;
    const bool has2 = (p2 < 169);
    const int i0 = p0 / 13, j0 = p0 - i0 * 13;
    const int i1 = p1 / 13, j1 = p1 - i1 * 13;
    const int i2 = p2 / 13, j2 = p2 - i2 * 13;   // used under has2

    for (int pp = 0; pp < 4; ++pp) {
        const int r = r_start + blockIdx.x * 16 + pp * 4 + w;
        const int nn = r & 7;
        const int jj = (r >> 3) & 63;
        const int ii = r >> 9;

        __syncthreads();   // guard inc_s / hi_s / lo_s reuse across pp
        if (lane < 13) {
            if (lane < 12) {
                const float* px = x + ((size_t)(nn * 12 + lane) * 1600 + ii * 64 + jj) * 5;
                float prev = 0.0f;
                #pragma unroll
                for (int l = 0; l < 5; ++l) {
                    float v = px[l];
                    inc_s[w][l][lane] = v - prev;
                    prev = v;
                }
            } else {
                inc_s[w][0][12] = 0.0f;
                #pragma unroll
                for (int l = 1; l < 5; ++l) inc_s[w][l][12] = 0.25f;
            }
        }
        __syncthreads();

        float s1i0 = 0.0f, s1i1 = 0.0f, s1i2 = 0.0f;
        float s2p0 = 0.0f, s2p1 = 0.0f, s2p2 = 0.0f;
        float s1own = 0.0f;
        float s3a[13], s3b[13], s3c[13];
        #pragma unroll
        for (int k = 0; k < 13; ++k) { s3a[k] = 0.0f; s3b[k] = 0.0f; s3c[k] = 0.0f; }

        for (int l = 0; l < 5; ++l) {
            float dxl[13];
            #pragma unroll
            for (int k = 0; k < 13; ++k) dxl[k] = inc_s[w][l][k];

            {   // pair 0
                float dxi = inc_s[w][l][i0];
                float dxj = inc_s[w][l][j0];
                float C   = s2p0 + 0.5f * dxj * (s1i0 + dxi * (1.0f / 3.0f));
                #pragma unroll
                for (int k = 0; k < 13; ++k) s3a[k] += dxl[k] * C;
                s2p0 += s1i0 * dxj + 0.5f * dxi * dxj;
                s1i0 += dxi;
            }
            {   // pair 1
                float dxi = inc_s[w][l][i1];
                float dxj = inc_s[w][l][j1];
                float C   = s2p1 + 0.5f * dxj * (s1i1 + dxi * (1.0f / 3.0f));
                #pragma unroll
                for (int k = 0; k < 13; ++k) s3b[k] += dxl[k] * C;
                s2p1 += s1i1 * dxj + 0.5f * dxi * dxj;
                s1i1 += dxi;
            }
            if (has2) {   // pair 2
                float dxi = inc_s[w][l][i2];
                float dxj = inc_s[w][l][j2];
                float C   = s2p2 + 0.5f * dxj * (s1i2 + dxi * (1.0f / 3.0f));
                #pragma unroll
                for (int k = 0; k < 13; ++k) s3c[k] += dxl[k] * C;
                s2p2 += s1i2 * dxj + 0.5f * dxi * dxj;
                s1i2 += dxi;
            }
            if (lane < 13) s1own += inc_s[w][l][lane];
        }

        // ---- write sig row into this wave's LDS row (hi/lo) ----
        if (lane < 13) split2(s1own, &hi_s[w][lane], &lo_s[w][lane]);
        split2(s2p0, &hi_s[w][13 + p0], &lo_s[w][13 + p0]);
        split2(s2p1, &hi_s[w][13 + p1], &lo_s[w][13 + p1]);
        if (has2) split2(s2p2, &hi_s[w][13 + p2], &lo_s[w][13 + p2]);
        #pragma unroll
        for (int k = 0; k < 13; ++k) split2(s3a[k], &hi_s[w][182 + p0 * 13 + k], &lo_s[w][182 + p0 * 13 + k]);
        #pragma unroll
        for (int k = 0; k < 13; ++k) split2(s3b[k], &hi_s[w][182 + p1 * 13 + k], &lo_s[w][182 + p1 * 13 + k]);
        if (has2) {
            #pragma unroll
            for (int k = 0; k < 13; ++k) split2(s3c[k], &hi_s[w][182 + p2 * 13 + k], &lo_s[w][182 + p2 * 13 + k]);
        }
        if (lane < KPAD - SIGC) {   // zero pad 2379..2431
            hi_s[w][SIGC + lane] = __float2bfloat16(0.0f);
            lo_s[w][SIGC + lane] = __float2bfloat16(0.0f);
        }

        __syncthreads();   // all 4 rows complete before cooperative copy-out

        // ---- block-cooperative coalesced copy-out (64B bursts) ----
        const int rtl = blockIdx.x;
        const int rr = t & 3, ks = (t >> 2) & 3, ts = t >> 4;
        #pragma unroll
        for (int it2 = 0; it2 < 5; ++it2) {
            int kt = it2 * 16 + ts;
            if (kt < NKT) {
                size_t off = ((size_t)rtl * NKT + kt) * 512 + ks * 128 + (pp * 4 + rr) * 8;
                int lidx = kt * 32 + ks * 8;
                *reinterpret_cast<int4*>(Ah + off)  = *reinterpret_cast<const int4*>(&hi_s[rr][lidx]);
                *reinterpret_cast<int4*>(Al_ + off) = *reinterpret_cast<const int4*>(&lo_s[rr][lidx]);
            }
        }
    }
}

// ---------------------------------------------------------------------------
// Split-bf16 GEMM, BM=64 x BN=128, split-K=2:
// P[ksp][m][o] = sum_{k in half} AhWh + AhWl + AlWh   (fp32 partials)
// bid = q*32 + ksp*16 + h*8 + x8, mIdx = q*8+x8 -> all 4 blocks of an
// m-block share bid%8 (same XCD slot): A's 2nd n-half read hits L2.
// 4 waves 2m x 2n (each 32x64 = 2x4 frags); double-buffered 48KB LDS;
// 1KB-tile lane-linear global_load_lds staging; coalesced fp32 P stores.
// ---------------------------------------------------------------------------
__global__ __launch_bounds__(256) void gemm_kernel(const __hip_bfloat16* __restrict__ Ah,
                                                   const __hip_bfloat16* __restrict__ Al_,
                                                   const __hip_bfloat16* __restrict__ Wh,
                                                   const __hip_bfloat16* __restrict__ Wl,
                                                   float* __restrict__ P,
                                                   int chunk_alloc, int nmblk)
{
    __shared__ __align__(16) __hip_bfloat16 L[2][24 * 512];   // 48 KB

    const int bid = blockIdx.x;
    const int x8 = bid & 7;
    const int h = (bid >> 3) & 1;
    const int ksp = (bid >> 4) & 1;
    const int q = bid >> 5;
    const int mIdx = q * 8 + x8;
    if (mIdx >= nmblk) return;

    const int t = threadIdx.x;
    const int lane = t & 63;
    const int w = t >> 6;
    const int wm = w >> 1, wn = w & 1;
    const int rt0 = mIdx * 4;      // 4 m-row-tiles
    const int nt0 = h * 8;         // 8 n-row-tiles
    const int kt0 = ksp * NKT_HALF;

    f32x4 acc[2][4] = {};

    // wave w stages tiles w*6..w*6+5: 0-3 Ah | 4-7 Al | 8-15 Wh | 16-23 Wl
    auto stage = [&](int buf, int kt) {
        #pragma unroll
        for (int s = 0; s < 6; ++s) {
            int tt = w * 6 + s;
            const __hip_bfloat16* g;
            if (tt < 4)       g = Ah  + ((size_t)(rt0 + tt)      * NKT + kt) * 512;
            else if (tt < 8)  g = Al_ + ((size_t)(rt0 + tt - 4)  * NKT + kt) * 512;
            else if (tt < 16) g = Wh  + ((size_t)(nt0 + tt - 8)  * NKT + kt) * 512;
            else              g = Wl  + ((size_t)(nt0 + tt - 16) * NKT + kt) * 512;
            gload_lds16(g + lane * 8, &L[buf][tt * 512]);
        }
    };

    stage(0, kt0);
    int cur = 0;
    __syncthreads();

    for (int kk = 0; kk < NKT_HALF; ++kk) {
        if (kk + 1 < NKT_HALF) stage(cur ^ 1, kt0 + kk + 1);   // issue-early prefetch

        const int fb = (lane >> 4) * 128 + (lane & 15) * 8;
        s16x8 ah[2], al4[2], bh[4], bl4[4];
        #pragma unroll
        for (int mm = 0; mm < 2; ++mm) {
            int base = (2 * wm + mm) * 512 + fb;
            ah[mm]  = *reinterpret_cast<const s16x8*>(&L[cur][base]);
            al4[mm] = *reinterpret_cast<const s16x8*>(&L[cur][2048 + base]);
        }
        #pragma unroll
        for (int nn = 0; nn < 4; ++nn) {
            int base = (4 * wn + nn) * 512 + fb;
            bh[nn]  = *reinterpret_cast<const s16x8*>(&L[cur][4096 + base]);
            bl4[nn] = *reinterpret_cast<const s16x8*>(&L[cur][8192 + base]);
        }

        #pragma unroll
        for (int mm = 0; mm < 2; ++mm)
            #pragma unroll
            for (int nn = 0; nn < 4; ++nn) {
                acc[mm][nn] = __builtin_amdgcn_mfma_f32_16x16x32_bf16(ah[mm],  bh[nn],  acc[mm][nn], 0, 0, 0);
                acc[mm][nn] = __builtin_amdgcn_mfma_f32_16x16x32_bf16(ah[mm],  bl4[nn], acc[mm][nn], 0, 0, 0);
                acc[mm][nn] = __builtin_amdgcn_mfma_f32_16x16x32_bf16(al4[mm], bh[nn],  acc[mm][nn], 0, 0, 0);
            }

        __syncthreads();
        cur ^= 1;
    }

    // ---- epilogue: coalesced fp32 partial stores ----
    // C/D layout: col=lane&15, row=(lane>>4)*4+reg
    float* Pb = P + ((size_t)ksp * chunk_alloc + mIdx * 64) * 256 + h * 128;
    #pragma unroll
    for (int mm = 0; mm < 2; ++mm)
        #pragma unroll
        for (int nn = 0; nn < 4; ++nn) {
            int o = wn * 64 + nn * 16 + (lane & 15);
            #pragma unroll
            for (int rr = 0; rr < 4; ++rr) {
                int p = wm * 32 + mm * 16 + (lane >> 4) * 4 + rr;
                Pb[(size_t)p * 256 + o] = acc[mm][nn][rr];
            }
        }
}

// ---------------------------------------------------------------------------
// Reduce: out = P0 + P1 + bias, scattered to out[ni][o][ii][jj].
// One block per 64-path m-block; float4 out stores; P reads L2-hot.
// ---------------------------------------------------------------------------
__global__ __launch_bounds__(256) void reduce_kernel(const float* __restrict__ P,
                                                     const float* __restrict__ b,
                                                     float* __restrict__ out,
                                                     int chunk_alloc, int r_start)
{
    const int mb = blockIdx.x;
    const int pbase = r_start + mb * 64;
    const int ii = pbase >> 9;
    const int jj0 = (pbase >> 3) & 63;
    const int t = threadIdx.x;
    const int ol = t >> 1, hh = t & 1;

    const float* P0 = P + (size_t)mb * 64 * 256;
    const float* P1 = P0 + (size_t)chunk_alloc * 256;

    #pragma unroll
    for (int oh = 0; oh < 2; ++oh) {
        int o = oh * 128 + ol;
        float bo = b[o];
        #pragma unroll
        for (int c = 0; c < 4; ++c) {
            int ni = hh * 4 + c;
            float v[8];
            #pragma unroll
            for (int qq = 0; qq < 8; ++qq) {
                size_t idx = (size_t)(qq * 8 + ni) * 256 + o;
                v[qq] = P0[idx] + P1[idx] + bo;
            }
            float* dst = out + (size_t)(ni * 256 + o) * 1600 + ii * 64 + jj0;
            *reinterpret_cast<float4*>(dst)     = make_float4(v[0], v[1], v[2], v[3]);
            *reinterpret_cast<float4*>(dst + 4) = make_float4(v[4], v[5], v[6], v[7]);
        }
    }
}

// ---------------------------------------------------------------------------
extern "C" void kernel_launch(void* const* d_in, const int* in_sizes, int n_in,
                              void* d_out, int out_size, void* d_ws, size_t ws_size,
                              hipStream_t stream)
{
    const float* x = (const float*)d_in[0];
    const float* W = (const float*)d_in[1];
    const float* b = (const float*)d_in[2];
    float* out = (float*)d_out;

    char* ws = (char*)d_ws;
    __hip_bfloat16* Wh = (__hip_bfloat16*)ws;
    __hip_bfloat16* Wl = Wh + (size_t)16 * NKT * 512;
    size_t a_off = (((size_t)16 * NKT * 512 * 2 * 2) + 255) & ~(size_t)255;

    // per-chunk bytes/path: A hi/lo (KPAD*2*2) + P fp32 (2*256*4)
    size_t avail = (ws_size > a_off) ? ws_size - a_off : 0;
    long long maxp = (long long)(avail / ((size_t)KPAD * 4 + 2048));
    int chunk = (int)((maxp / 64) * 64);
    if (chunk > NPATH) chunk = NPATH;
    if (chunk < 64) chunk = 64;

    __hip_bfloat16* Ah = (__hip_bfloat16*)(ws + a_off);
    __hip_bfloat16* Al_ = Ah + (size_t)chunk * KPAD;
    float* P = (float*)(Al_ + (size_t)chunk * KPAD);

    wconv_kernel<<<dim3(10, 256), 256, 0, stream>>>(W, Wh, Wl);

    for (int r0 = 0; r0 < NPATH; r0 += chunk) {
        int cnt = NPATH - r0;
        if (cnt > chunk) cnt = chunk;
        int nmblk = cnt / 64;
        int nblk = ((nmblk + 7) / 8) * 32;
        sig_kernel<<<dim3(cnt / 16), 256, 0, stream>>>(x, Ah, Al_, r0);
        gemm_kernel<<<dim3(nblk), 256, 0, stream>>>(Ah, Al_, Wh, Wl, P, chunk, nmblk);
        reduce_kernel<<<dim3(cnt / 64), 256, 0, stream>>>(P, b, out, chunk, r0);
    }
}